// Round 23
// baseline (2689.415 us; speedup 1.0000x reference)
//
#include <hip/hip_runtime.h>
#include <math.h>

#define BATCH 4
#define CIN 64
#define S 48
#define SPAT (48*48*48)
#define HEADS 4
#define HC 24
#define HD 96
#define OCT 8
#define M 8
#define NPTS 13824

// ---------------- Kernel 1: pooled centers + agg init (round-2 exact) --------
__global__ __launch_bounds__(256) void k_centers(
    const float* __restrict__ x, const float* __restrict__ Wf,
    const float* __restrict__ bfp, const float* __restrict__ Wv,
    const float* __restrict__ bvp,
    float* __restrict__ cnorm, float* __restrict__ aggnum,
    float* __restrict__ aggden) {
  int blk = blockIdx.x;
  int b = blk >> 6, q = blk & 63;
  int qw = q >> 4, qh = (q >> 2) & 3, qd = q & 3;
  int t = threadIdx.x;
  int lane = t & 63, wv = t >> 6;

  __shared__ float xpool[CIN];
  __shared__ float fc[HD], vc[HD], rinvs[HEADS];

  const float* xb = x + (size_t)b * CIN * SPAT;
  for (int cin = wv; cin < CIN; cin += 4) {
    const float* xc = xb + (size_t)cin * SPAT;
    float p = 0.f;
    for (int j = lane; j < 1728; j += 64) {
      int lw = j / 144, lh = (j / 12) % 12, ld = j % 12;
      int w = qw * 12 + lw, h = qh * 12 + lh, d = qd * 12 + ld;
      p += xc[(w * S + h) * S + d];
    }
#pragma unroll
    for (int s = 32; s; s >>= 1) p += __shfl_down(p, s, 64);
    if (lane == 0) xpool[cin] = p * (1.f / 1728.f);
  }
  __syncthreads();

  if (t < 192) {
    int k = (t < 96) ? t : t - 96;
    const float* Wrow = ((t < 96) ? Wf : Wv) + k * CIN;
    float acc = (t < 96) ? bfp[k] : bvp[k];
#pragma unroll
    for (int c = 0; c < CIN; c++) acc += Wrow[c] * xpool[c];
    if (t < 96) fc[k] = acc; else vc[k] = acc;
  }
  __syncthreads();

  if (t < HEADS) {
    float ss = 0.f;
#pragma unroll
    for (int c = 0; c < HC; c++) { float v = fc[t * HC + c]; ss += v * v; }
    rinvs[t] = 1.f / fmaxf(sqrtf(ss), 1e-12f);
  }
  __syncthreads();

  int o = ((qw >> 1) << 2) | ((qh >> 1) << 1) | (qd >> 1);
  int m = ((qw & 1) << 2) | ((qh & 1) << 1) | (qd & 1);
  if (t < HD) {
    int e = t / HC, c = t % HC;
    size_t oidx = ((((size_t)b * HEADS + e) * OCT + o) * M + m) * HC + c;
    cnorm[oidx] = fc[t] * rinvs[e];
    aggnum[oidx] = vc[t];
  }
  if (t < HEADS) {
    aggden[(((size_t)b * HEADS + t) * OCT + o) * M + m] = 1.0f;
  }
}

// ---------------- Kernel 2: round-2 k_assign EXACT (proven 215.6 us) ----------
__global__ __launch_bounds__(256) void k_assign(
    const float* __restrict__ x, const float* __restrict__ Wf,
    const float* __restrict__ bf, const float* __restrict__ Wv,
    const float* __restrict__ bv, const float* __restrict__ cnorm,
    const float* __restrict__ salpha, const float* __restrict__ sbeta,
    float* __restrict__ aggnum, float* __restrict__ aggden,
    float* __restrict__ simbuf, unsigned char* __restrict__ idxbuf) {
  int blk = blockIdx.x;
  int chunk = blk % 54;
  int bo = blk / 54;
  int o = bo & 7, b = bo >> 3;
  int t = threadIdx.x;
  int n = chunk * 256 + t;
  int wp = n / 576, hp = (n / 24) % 24, dp = n % 24;
  int ow = (o >> 2) & 1, oh = (o >> 1) & 1, od = o & 1;
  int w = ow * 24 + wp, h = oh * 24 + hp, d = od * 24 + dp;

  __shared__ float lagg[HEADS][M][HC + 1];
  for (int i = t; i < HEADS * M * (HC + 1); i += 256) ((float*)lagg)[i] = 0.f;
  __syncthreads();

  float xr[CIN];
  const float* xb = x + (size_t)b * CIN * SPAT + (size_t)(w * S + h) * S + d;
#pragma unroll
  for (int c = 0; c < CIN; c++) xr[c] = xb[(size_t)c * SPAT];

  float alpha = salpha[0], beta = sbeta[0];

  for (int e = 0; e < HEADS; e++) {
    float f[HC];
#pragma unroll
    for (int c = 0; c < HC; c++) f[c] = bf[e * HC + c];
#pragma unroll
    for (int ci = 0; ci < CIN; ci++) {
      float xv = xr[ci];
#pragma unroll
      for (int c = 0; c < HC; c++) f[c] += Wf[(e * HC + c) * CIN + ci] * xv;
    }
    float ss = 0.f;
#pragma unroll
    for (int c = 0; c < HC; c++) ss += f[c] * f[c];
    float rinv = 1.f / fmaxf(sqrtf(ss), 1e-12f);

    const float* cn = cnorm + (((size_t)b * HEADS + e) * OCT + o) * M * HC;
    float best = -1.f;
    int bm = 0;
#pragma unroll
    for (int m = 0; m < M; m++) {
      float dt = 0.f;
#pragma unroll
      for (int c = 0; c < HC; c++) dt += cn[m * HC + c] * f[c];
      float cosv = dt * rinv;
      float sim = 1.f / (1.f + __expf(-(beta + alpha * cosv)));
      if (sim > best) { best = sim; bm = m; }
    }

    size_t pidx = (((size_t)b * HEADS + e) * OCT + o) * (size_t)NPTS + n;
    simbuf[pidx] = best;
    idxbuf[pidx] = (unsigned char)bm;

    float v[HC];
#pragma unroll
    for (int c = 0; c < HC; c++) v[c] = bv[e * HC + c];
#pragma unroll
    for (int ci = 0; ci < CIN; ci++) {
      float xv = xr[ci];
#pragma unroll
      for (int c = 0; c < HC; c++) v[c] += Wv[(e * HC + c) * CIN + ci] * xv;
    }
#pragma unroll
    for (int c = 0; c < HC; c++) atomicAdd(&lagg[e][bm][c], best * v[c]);
    atomicAdd(&lagg[e][bm][HC], best);
  }
  __syncthreads();

  for (int i = t; i < HEADS * M * (HC + 1); i += 256) {
    int e = i / (M * (HC + 1));
    int r = i % (M * (HC + 1));
    int m = r / (HC + 1), c = r % (HC + 1);
    float val = lagg[e][m][c];
    size_t base = (((size_t)b * HEADS + e) * OCT + o) * M + m;
    if (c < HC) atomicAdd(&aggnum[base * HC + c], val);
    else        atomicAdd(&aggden[base], val);
  }
}

// ---------------- Kernel 3: k_out, LDS-pre + channel-parallel projection ------
// 64 points/block. pre in LDS (pad 97 -> conflict-free); wave w owns out
// channels 16w..16w+15 so Wp rows are wave-uniform (scalar loads). VGPR ~48
// (vs 102 with pre[96] in regs) -> high occupancy. k ascending per dot.
__global__ __launch_bounds__(256) void k_out(
    const float* __restrict__ Wp, const float* __restrict__ bp,
    const float* __restrict__ aggnum, const float* __restrict__ aggden,
    const float* __restrict__ simbuf, const unsigned char* __restrict__ idxbuf,
    float* __restrict__ out) {
  int blk = blockIdx.x;
  int chunk = blk % 216;
  int bo = blk / 216;
  int o = bo & 7, b = bo >> 3;
  int t = threadIdx.x;

  __shared__ float lds_agg[HEADS][M][HC];
  __shared__ float lds_den[HEADS][M];
  __shared__ float rat_l[64][4];
  __shared__ unsigned char mm_l[64][4];
  __shared__ float pre_l[64][97];

  for (int i = t; i < HEADS * M * HC; i += 256) {
    int e = i / (M * HC), r = i % (M * HC);
    int m = r / HC, c = r % HC;
    ((float*)lds_agg)[i] = aggnum[((((size_t)b * HEADS + e) * OCT + o) * M + m) * HC + c];
  }
  if (t < HEADS * M) {
    int e = t / M, m = t % M;
    ((float*)lds_den)[t] = aggden[(((size_t)b * HEADS + e) * OCT + o) * M + m];
  }
  __syncthreads();

  // phase 1: per-point gather (threads 0-63)
  if (t < 64) {
    int n = chunk * 64 + t;
#pragma unroll
    for (int e = 0; e < HEADS; e++) {
      size_t pidx = (((size_t)b * HEADS + e) * OCT + o) * (size_t)NPTS + n;
      float s = simbuf[pidx];
      int m = idxbuf[pidx];
      mm_l[t][e] = (unsigned char)m;
      rat_l[t][e] = s / lds_den[e][m];
    }
  }
  __syncthreads();

  // phase 2: fill pre_l[pt][k] = agg[e][mm][c] * rat[e], k = e*24+c
  for (int i = t; i < 64 * HD; i += 256) {
    int pt = i / HD, k = i % HD;
    int e = k / HC, c = k % HC;
    pre_l[pt][k] = lds_agg[e][mm_l[pt][e]][c] * rat_l[pt][e];
  }
  __syncthreads();

  // phase 3: wave w -> out channels 16w..16w+15; pt = lane
  int pt = t & 63;
  int wv = t >> 6;
  int np = chunk * 64 + pt;
  int wp = np / 576, hp = (np / 24) % 24, dp = np % 24;
  int ow = (o >> 2) & 1, oh = (o >> 1) & 1, od = o & 1;
  float* ob = out + (size_t)b * CIN * SPAT
            + (size_t)((ow * 24 + wp) * S + (oh * 24 + hp)) * S + (od * 24 + dp);

#pragma unroll 1
  for (int ci = 0; ci < 16; ci++) {
    int co = wv * 16 + ci;
    const float* wrow = Wp + co * HD;   // wave-uniform -> scalar loads
    float acc = bp[co];
#pragma unroll
    for (int k = 0; k < HD; k++) acc += wrow[k] * pre_l[pt][k];
    ob[(size_t)co * SPAT] = acc;
  }
}

extern "C" void kernel_launch(void* const* d_in, const int* in_sizes, int n_in,
                              void* d_out, int out_size, void* d_ws, size_t ws_size,
                              hipStream_t stream) {
  const float* x  = (const float*)d_in[0];
  const float* Wf = (const float*)d_in[1];
  const float* bf = (const float*)d_in[2];
  const float* Wv = (const float*)d_in[3];
  const float* bv = (const float*)d_in[4];
  const float* Wp = (const float*)d_in[5];
  const float* bp = (const float*)d_in[6];
  const float* sa = (const float*)d_in[7];
  const float* sb = (const float*)d_in[8];
  float* out = (float*)d_out;

  // Round-2 proven layout (9.05 MB).
  float* ws = (float*)d_ws;
  float* cnorm  = ws;                    // 24576 f
  float* aggnum = cnorm + 24576;         // 24576 f
  float* aggden = aggnum + 24576;        // 1024 f
  float* simbuf = aggden + 1024;         // 1769472 f
  unsigned char* idxbuf = (unsigned char*)(simbuf + 1769472);  // 1769472 bytes

  k_centers<<<BATCH * 64, 256, 0, stream>>>(x, Wf, bf, Wv, bv, cnorm, aggnum, aggden);
  k_assign<<<BATCH * OCT * 54, 256, 0, stream>>>(x, Wf, bf, Wv, bv, cnorm, sa, sb,
                                                 aggnum, aggden, simbuf, idxbuf);
  k_out<<<BATCH * OCT * 216, 256, 0, stream>>>(Wp, bp, aggnum, aggden,
                                               simbuf, idxbuf, out);
}

// Round 24
// 2606.094 us; speedup vs baseline: 1.0320x; 1.0320x over previous
//
#include <hip/hip_runtime.h>
#include <math.h>

#define BATCH 4
#define CIN 64
#define S 48
#define SPAT (48*48*48)
#define HEADS 4
#define HC 24
#define HD 96
#define OCT 8
#define M 8
#define NPTS 13824

// ---------------- Kernel 1: pooled centers + agg init (round-2 exact) --------
__global__ __launch_bounds__(256) void k_centers(
    const float* __restrict__ x, const float* __restrict__ Wf,
    const float* __restrict__ bfp, const float* __restrict__ Wv,
    const float* __restrict__ bvp,
    float* __restrict__ cnorm, float* __restrict__ aggnum,
    float* __restrict__ aggden) {
  int blk = blockIdx.x;
  int b = blk >> 6, q = blk & 63;
  int qw = q >> 4, qh = (q >> 2) & 3, qd = q & 3;
  int t = threadIdx.x;
  int lane = t & 63, wv = t >> 6;

  __shared__ float xpool[CIN];
  __shared__ float fc[HD], vc[HD], rinvs[HEADS];

  const float* xb = x + (size_t)b * CIN * SPAT;
  for (int cin = wv; cin < CIN; cin += 4) {
    const float* xc = xb + (size_t)cin * SPAT;
    float p = 0.f;
    for (int j = lane; j < 1728; j += 64) {
      int lw = j / 144, lh = (j / 12) % 12, ld = j % 12;
      int w = qw * 12 + lw, h = qh * 12 + lh, d = qd * 12 + ld;
      p += xc[(w * S + h) * S + d];
    }
#pragma unroll
    for (int s = 32; s; s >>= 1) p += __shfl_down(p, s, 64);
    if (lane == 0) xpool[cin] = p * (1.f / 1728.f);
  }
  __syncthreads();

  if (t < 192) {
    int k = (t < 96) ? t : t - 96;
    const float* Wrow = ((t < 96) ? Wf : Wv) + k * CIN;
    float acc = (t < 96) ? bfp[k] : bvp[k];
#pragma unroll
    for (int c = 0; c < CIN; c++) acc += Wrow[c] * xpool[c];
    if (t < 96) fc[k] = acc; else vc[k] = acc;
  }
  __syncthreads();

  if (t < HEADS) {
    float ss = 0.f;
#pragma unroll
    for (int c = 0; c < HC; c++) { float v = fc[t * HC + c]; ss += v * v; }
    rinvs[t] = 1.f / fmaxf(sqrtf(ss), 1e-12f);
  }
  __syncthreads();

  int o = ((qw >> 1) << 2) | ((qh >> 1) << 1) | (qd >> 1);
  int m = ((qw & 1) << 2) | ((qh & 1) << 1) | (qd & 1);
  if (t < HD) {
    int e = t / HC, c = t % HC;
    size_t oidx = ((((size_t)b * HEADS + e) * OCT + o) * M + m) * HC + c;
    cnorm[oidx] = fc[t] * rinvs[e];
    aggnum[oidx] = vc[t];
  }
  if (t < HEADS) {
    aggden[(((size_t)b * HEADS + t) * OCT + o) * M + m] = 1.0f;
  }
}

// ---------------- Kernel 2: round-2 k_assign + anti-spill launch bound --------
// Round-23 ran this EXACT arithmetic at 2233us because the current compiler
// allocated only 92 VGPRs and spilled xr[64] to scratch (round-2's container
// allocated 136 VGPR -> 215.6us). LDS is trivial (3.3KB) so residency is
// ~2 blocks/CU regardless; (256,2) raises the VGPR budget so xr/f/v stay
// in registers.
__global__ __launch_bounds__(256, 2) void k_assign(
    const float* __restrict__ x, const float* __restrict__ Wf,
    const float* __restrict__ bf, const float* __restrict__ Wv,
    const float* __restrict__ bv, const float* __restrict__ cnorm,
    const float* __restrict__ salpha, const float* __restrict__ sbeta,
    float* __restrict__ aggnum, float* __restrict__ aggden,
    float* __restrict__ simbuf, unsigned char* __restrict__ idxbuf) {
  int blk = blockIdx.x;
  int chunk = blk % 54;
  int bo = blk / 54;
  int o = bo & 7, b = bo >> 3;
  int t = threadIdx.x;
  int n = chunk * 256 + t;
  int wp = n / 576, hp = (n / 24) % 24, dp = n % 24;
  int ow = (o >> 2) & 1, oh = (o >> 1) & 1, od = o & 1;
  int w = ow * 24 + wp, h = oh * 24 + hp, d = od * 24 + dp;

  __shared__ float lagg[HEADS][M][HC + 1];
  for (int i = t; i < HEADS * M * (HC + 1); i += 256) ((float*)lagg)[i] = 0.f;
  __syncthreads();

  float xr[CIN];
  const float* xb = x + (size_t)b * CIN * SPAT + (size_t)(w * S + h) * S + d;
#pragma unroll
  for (int c = 0; c < CIN; c++) xr[c] = xb[(size_t)c * SPAT];

  float alpha = salpha[0], beta = sbeta[0];

  for (int e = 0; e < HEADS; e++) {
    float f[HC];
#pragma unroll
    for (int c = 0; c < HC; c++) f[c] = bf[e * HC + c];
#pragma unroll
    for (int ci = 0; ci < CIN; ci++) {
      float xv = xr[ci];
#pragma unroll
      for (int c = 0; c < HC; c++) f[c] += Wf[(e * HC + c) * CIN + ci] * xv;
    }
    float ss = 0.f;
#pragma unroll
    for (int c = 0; c < HC; c++) ss += f[c] * f[c];
    float rinv = 1.f / fmaxf(sqrtf(ss), 1e-12f);

    const float* cn = cnorm + (((size_t)b * HEADS + e) * OCT + o) * M * HC;
    float best = -1.f;
    int bm = 0;
#pragma unroll
    for (int m = 0; m < M; m++) {
      float dt = 0.f;
#pragma unroll
      for (int c = 0; c < HC; c++) dt += cn[m * HC + c] * f[c];
      float cosv = dt * rinv;
      float sim = 1.f / (1.f + __expf(-(beta + alpha * cosv)));
      if (sim > best) { best = sim; bm = m; }
    }

    size_t pidx = (((size_t)b * HEADS + e) * OCT + o) * (size_t)NPTS + n;
    simbuf[pidx] = best;
    idxbuf[pidx] = (unsigned char)bm;

    float v[HC];
#pragma unroll
    for (int c = 0; c < HC; c++) v[c] = bv[e * HC + c];
#pragma unroll
    for (int ci = 0; ci < CIN; ci++) {
      float xv = xr[ci];
#pragma unroll
      for (int c = 0; c < HC; c++) v[c] += Wv[(e * HC + c) * CIN + ci] * xv;
    }
#pragma unroll
    for (int c = 0; c < HC; c++) atomicAdd(&lagg[e][bm][c], best * v[c]);
    atomicAdd(&lagg[e][bm][HC], best);
  }
  __syncthreads();

  for (int i = t; i < HEADS * M * (HC + 1); i += 256) {
    int e = i / (M * (HC + 1));
    int r = i % (M * (HC + 1));
    int m = r / (HC + 1), c = r % (HC + 1);
    float val = lagg[e][m][c];
    size_t base = (((size_t)b * HEADS + e) * OCT + o) * M + m;
    if (c < HC) atomicAdd(&aggnum[base * HC + c], val);
    else        atomicAdd(&aggden[base], val);
  }
}

// ---------------- Kernel 3: dispatch + unfold + output projection (round-2) ----
__global__ __launch_bounds__(256, 2) void k_out(
    const float* __restrict__ Wp, const float* __restrict__ bp,
    const float* __restrict__ aggnum, const float* __restrict__ aggden,
    const float* __restrict__ simbuf, const unsigned char* __restrict__ idxbuf,
    float* __restrict__ out) {
  int blk = blockIdx.x;
  int b = blk / 432;
  int p = (blk % 432) * 256 + threadIdx.x;
  int w = p / 2304, h = (p / 48) % 48, d = p % 48;
  int ow = w / 24, oh = h / 24, od = d / 24;
  int o = ow * 4 + oh * 2 + od;
  int wp = w % 24, hp = h % 24, dp = d % 24;
  int n = (wp * 24 + hp) * 24 + dp;

  float pre[HD];
#pragma unroll
  for (int e = 0; e < HEADS; e++) {
    size_t pidx = (((size_t)b * HEADS + e) * OCT + o) * (size_t)NPTS + n;
    float s = simbuf[pidx];
    int m = idxbuf[pidx];
    size_t aidx = (((size_t)b * HEADS + e) * OCT + o) * M + m;
    float den = aggden[aidx];
    float sc = s / den;
    const float* nm = aggnum + aidx * HC;
#pragma unroll
    for (int c = 0; c < HC; c++) pre[e * HC + c] = nm[c] * sc;
  }

  float* ob = out + (size_t)b * CIN * SPAT + p;
  for (int co = 0; co < CIN; co++) {
    float acc = bp[co];
#pragma unroll
    for (int k = 0; k < HD; k++) acc += Wp[co * HD + k] * pre[k];
    ob[(size_t)co * SPAT] = acc;
  }
}

extern "C" void kernel_launch(void* const* d_in, const int* in_sizes, int n_in,
                              void* d_out, int out_size, void* d_ws, size_t ws_size,
                              hipStream_t stream) {
  const float* x  = (const float*)d_in[0];
  const float* Wf = (const float*)d_in[1];
  const float* bf = (const float*)d_in[2];
  const float* Wv = (const float*)d_in[3];
  const float* bv = (const float*)d_in[4];
  const float* Wp = (const float*)d_in[5];
  const float* bp = (const float*)d_in[6];
  const float* sa = (const float*)d_in[7];
  const float* sb = (const float*)d_in[8];
  float* out = (float*)d_out;

  // Round-2 proven layout (9.05 MB).
  float* ws = (float*)d_ws;
  float* cnorm  = ws;                    // 24576 f
  float* aggnum = cnorm + 24576;         // 24576 f
  float* aggden = aggnum + 24576;        // 1024 f
  float* simbuf = aggden + 1024;         // 1769472 f
  unsigned char* idxbuf = (unsigned char*)(simbuf + 1769472);  // 1769472 bytes

  k_centers<<<BATCH * 64, 256, 0, stream>>>(x, Wf, bf, Wv, bv, cnorm, aggnum, aggden);
  k_assign<<<BATCH * OCT * 54, 256, 0, stream>>>(x, Wf, bf, Wv, bv, cnorm, sa, sb,
                                                 aggnum, aggden, simbuf, idxbuf);
  k_out<<<BATCH * 432, 256, 0, stream>>>(Wp, bp, aggnum, aggden, simbuf, idxbuf, out);
}

// Round 25
// 425.805 us; speedup vs baseline: 6.3161x; 6.1204x over previous
//
#include <hip/hip_runtime.h>
#include <math.h>

#define BATCH 4
#define CIN 64
#define S 48
#define SPAT (48*48*48)
#define HEADS 4
#define HC 24
#define HD 96
#define OCT 8
#define M 8
#define NPTS 13824

typedef __attribute__((ext_vector_type(8))) short bf16x8;
typedef __attribute__((ext_vector_type(4))) float f32x4;

__device__ __forceinline__ unsigned short f2bf(float f) {
  unsigned int u = __float_as_uint(f);
  unsigned int r = (u + 0x7fffu + ((u >> 16) & 1u)) >> 16;
  return (unsigned short)r;
}
__device__ __forceinline__ float bf2f(unsigned short s) {
  return __uint_as_float(((unsigned int)s) << 16);
}

// ---------------- Kernel 0: weight prep -> frag-layout bf16 splits ----------------
__global__ __launch_bounds__(256) void k_prep(
    const float* __restrict__ Wf, const float* __restrict__ Wv,
    const float* __restrict__ Wp,
    unsigned short* __restrict__ wsA_h, unsigned short* __restrict__ wsA_m,
    unsigned short* __restrict__ wsP_h, unsigned short* __restrict__ wsP_l) {
  int t = threadIdx.x;
  int lane = t & 63, quad = t >> 6;
  int ri = lane & 15, g = lane >> 4;
  for (int rtq = 0; rtq < 4; rtq++) {
    int rt = quad * 4 + rtq;
    int R = rt * 16 + ri;
    int e = R >> 6, r64 = R & 63;
    for (int kb = 0; kb < 2; kb++) {
      unsigned int ph[4], pm[4];
      for (int jj = 0; jj < 4; jj++) {
        unsigned short h2[2], m2[2];
        for (int k2 = 0; k2 < 2; k2++) {
          int c = kb * 32 + g * 8 + jj * 2 + k2;
          float w = 0.f;
          if (r64 < 32) { if (r64 < HC) w = Wf[(e * HC + r64) * CIN + c]; }
          else          { int r2 = r64 - 32; if (r2 < HC) w = Wv[(e * HC + r2) * CIN + c]; }
          unsigned short h = f2bf(w);   float rm = w - bf2f(h);
          h2[k2] = h; m2[k2] = f2bf(rm);
        }
        ph[jj] = (unsigned)h2[0] | ((unsigned)h2[1] << 16);
        pm[jj] = (unsigned)m2[0] | ((unsigned)m2[1] << 16);
      }
      size_t base = ((size_t)(rt * 2 + kb) * 64 + lane) * 8;
      *(uint4*)(wsA_h + base) = make_uint4(ph[0], ph[1], ph[2], ph[3]);
      *(uint4*)(wsA_m + base) = make_uint4(pm[0], pm[1], pm[2], pm[3]);
    }
  }
  {
    int rt = quad;
    int R = rt * 16 + ri;
    for (int kb = 0; kb < 3; kb++) {
      unsigned int ph[4], pl[4];
      for (int jj = 0; jj < 4; jj++) {
        unsigned short h2[2], l2[2];
        for (int k2 = 0; k2 < 2; k2++) {
          int kk = kb * 32 + g * 8 + jj * 2 + k2;
          float w = Wp[R * HD + kk];
          unsigned short h = f2bf(w);
          h2[k2] = h; l2[k2] = f2bf(w - bf2f(h));
        }
        ph[jj] = (unsigned)h2[0] | ((unsigned)h2[1] << 16);
        pl[jj] = (unsigned)l2[0] | ((unsigned)l2[1] << 16);
      }
      size_t base = ((size_t)(rt * 3 + kb) * 64 + lane) * 8;
      *(uint4*)(wsP_h + base) = make_uint4(ph[0], ph[1], ph[2], ph[3]);
      *(uint4*)(wsP_l + base) = make_uint4(pl[0], pl[1], pl[2], pl[3]);
    }
  }
}

// ---------------- Kernel 1: pooled centers + agg init + G = cn^T Wf (2-way) ----
__global__ __launch_bounds__(256) void k_centers(
    const float* __restrict__ x, const float* __restrict__ Wf,
    const float* __restrict__ bfp, const float* __restrict__ Wv,
    const float* __restrict__ bvp,
    float* __restrict__ cnorm, float* __restrict__ aggnum,
    float* __restrict__ aggden,
    unsigned short* __restrict__ wsG_h, unsigned short* __restrict__ wsG_m,
    float* __restrict__ biasG) {
  int blk = blockIdx.x;
  int b = blk >> 6, q = blk & 63;
  int qw = q >> 4, qh = (q >> 2) & 3, qd = q & 3;
  int t = threadIdx.x;
  int lane = t & 63, wv = t >> 6;

  __shared__ float xpool[CIN];
  __shared__ float fc[HD], vc[HD], rinvs[HEADS];

  const float* xb = x + (size_t)b * CIN * SPAT;
  for (int cin = wv; cin < CIN; cin += 4) {
    const float* xc = xb + (size_t)cin * SPAT;
    float p = 0.f;
    for (int j = lane; j < 1728; j += 64) {
      int lw = j / 144, lh = (j / 12) % 12, ld = j % 12;
      int w = qw * 12 + lw, h = qh * 12 + lh, d = qd * 12 + ld;
      p += xc[(w * S + h) * S + d];
    }
#pragma unroll
    for (int s = 32; s; s >>= 1) p += __shfl_down(p, s, 64);
    if (lane == 0) xpool[cin] = p * (1.f / 1728.f);
  }
  __syncthreads();

  if (t < 192) {
    int k = (t < 96) ? t : t - 96;
    const float* Wrow = ((t < 96) ? Wf : Wv) + k * CIN;
    float acc = (t < 96) ? bfp[k] : bvp[k];
#pragma unroll
    for (int c = 0; c < CIN; c++) acc += Wrow[c] * xpool[c];
    if (t < 96) fc[k] = acc; else vc[k] = acc;
  }
  __syncthreads();

  if (t < HEADS) {
    float ss = 0.f;
#pragma unroll
    for (int c = 0; c < HC; c++) { float v = fc[t * HC + c]; ss += v * v; }
    rinvs[t] = 1.f / fmaxf(sqrtf(ss), 1e-12f);
  }
  __syncthreads();

  int o = ((qw >> 1) << 2) | ((qh >> 1) << 1) | (qd >> 1);
  int m = ((qw & 1) << 2) | ((qh & 1) << 1) | (qd & 1);
  if (t < HD) {
    int e = t / HC, c = t % HC;
    size_t oidx = ((((size_t)b * HEADS + e) * OCT + o) * M + m) * HC + c;
    cnorm[oidx] = fc[t] * rinvs[e];
    aggnum[oidx] = vc[t];
  }
  if (t < HEADS) {
    aggden[(((size_t)b * HEADS + t) * OCT + o) * M + m] = 1.0f;
  }
  {
    int e = t >> 6, c = t & 63;
    float cacc = 0.f;
#pragma unroll
    for (int r = 0; r < HC; r++)
      cacc += (fc[e * HC + r] * rinvs[e]) * Wf[(e * HC + r) * CIN + c];
    int kb = c >> 5, gq = (c >> 3) & 3, j = c & 7;
    size_t tile = (((size_t)b * HEADS + e) * OCT + o) * 2 + kb;
    size_t idx = (tile * 64 + gq * 16 + 8 + m) * 8 + j;
    unsigned short h = f2bf(cacc); float rm_ = cacc - bf2f(h);
    wsG_h[idx] = h; wsG_m[idx] = f2bf(rm_);
    if (c == 0) {
      float bacc = 0.f;
#pragma unroll
      for (int r = 0; r < HC; r++)
        bacc += (fc[e * HC + r] * rinvs[e]) * bfp[e * HC + r];
      biasG[(((size_t)b * HEADS + e) * OCT + o) * M + m] = bacc;
    }
  }
}

// ---------------- Kernel 2: MFMA (2-way x 2-way) + reg aggregation + oracle ----
__global__ __launch_bounds__(256, 2) void k_assign(
    const float* __restrict__ x, const float* __restrict__ Wf,
    const unsigned short* __restrict__ wsA_h,
    const unsigned short* __restrict__ wsA_m,
    const unsigned short* __restrict__ wsG_h,
    const unsigned short* __restrict__ wsG_m,
    const float* __restrict__ biasG,
    const float* __restrict__ bf_, const float* __restrict__ bv_,
    const float* __restrict__ cnorm,
    const float* __restrict__ salpha, const float* __restrict__ sbeta,
    float* __restrict__ aggnum, float* __restrict__ aggden,
    unsigned int* __restrict__ simidx) {
  int blk = blockIdx.x;
  int chunk = blk % 108;
  int bo = blk / 108;
  int o = bo & 7, b = bo >> 3;
  int t = threadIdx.x;
  int lane = t & 63;
  int wv = t >> 6;
  int p16 = lane & 15;
  int g = lane >> 4;
  int ri = lane & 15;
  int ow = (o >> 2) & 1, oh = (o >> 1) & 1, od = o & 1;

  __shared__ uint4 Bh[8][2][64], Bm[8][2][64];
  __shared__ float lds_agg[HEADS][M][HC];
  __shared__ float lds_den[HEADS][M];
  __shared__ float lds_fq[HEADS][16][HC];

  // ---- stage x tile as 2-way bf16 splits (2 threads per point) ----
  {
    int pidx = t >> 1, kbh = t & 1;
    int n0 = chunk * 128 + pidx;
    int wp = n0 / 576, hp = (n0 / 24) % 24, dp = n0 % 24;
    const float* xb = x + (size_t)b * CIN * SPAT
                    + (size_t)((ow * 24 + wp) * S + (oh * 24 + hp)) * S + (od * 24 + dp);
    int ptt = pidx >> 4, pw = pidx & 15;
    for (int gg = 0; gg < 4; gg++) {
      unsigned int ph[4], pm[4];
#pragma unroll
      for (int jj = 0; jj < 4; jj++) {
        unsigned short h2[2], m2[2];
#pragma unroll
        for (int k2 = 0; k2 < 2; k2++) {
          float v = xb[(size_t)(kbh * 32 + gg * 8 + jj * 2 + k2) * SPAT];
          unsigned short h = f2bf(v);   float rm = v - bf2f(h);
          h2[k2] = h; m2[k2] = f2bf(rm);
        }
        ph[jj] = (unsigned)h2[0] | ((unsigned)h2[1] << 16);
        pm[jj] = (unsigned)m2[0] | ((unsigned)m2[1] << 16);
      }
      Bh[ptt][kbh][gg * 16 + pw] = make_uint4(ph[0], ph[1], ph[2], ph[3]);
      Bm[ptt][kbh][gg * 16 + pw] = make_uint4(pm[0], pm[1], pm[2], pm[3]);
    }
  }

  // ---- A fragments: tile1 = f rows 16-23 (ri<8) | G rows (ri>=8) ----
  const bf16x8* AH = (const bf16x8*)wsA_h;
  const bf16x8* AM = (const bf16x8*)wsA_m;
  const bf16x8* GH = (const bf16x8*)wsG_h;
  const bf16x8* GM = (const bf16x8*)wsG_m;
  bf16x8 Fh[2][2], Fm[2][2], Vh[2][2], Vm[2][2];
#pragma unroll
  for (int kb = 0; kb < 2; kb++) {
    int rtf0 = ((wv * 4 + 0) * 2 + kb) * 64 + lane;
    Fh[0][kb] = AH[rtf0]; Fm[0][kb] = AM[rtf0];
    int rtf1 = ((wv * 4 + 1) * 2 + kb) * 64 + lane;
    size_t gt = ((((size_t)b * HEADS + wv) * OCT + o) * 2 + kb) * 64 + lane;
    Fh[1][kb] = (ri < 8) ? AH[rtf1] : GH[gt];
    Fm[1][kb] = (ri < 8) ? AM[rtf1] : GM[gt];
#pragma unroll
    for (int i = 0; i < 2; i++) {
      int rtv = ((wv * 4 + 2 + i) * 2 + kb) * 64 + lane;
      Vh[i][kb] = AH[rtv]; Vm[i][kb] = AM[rtv];
    }
  }

  float bF0[4], bF1[4], bV0[4], bV1[4];
#pragma unroll
  for (int reg = 0; reg < 4; reg++) {
    bF0[reg] = bf_[wv * HC + 4 * g + reg];
    bV0[reg] = bv_[wv * HC + 4 * g + reg];
    bF1[reg] = (g < 2) ? bf_[wv * HC + 16 + 4 * g + reg]
             : biasG[(((size_t)b * HEADS + wv) * OCT + o) * M + 4 * (g - 2) + reg];
    bV1[reg] = (g < 2) ? bv_[wv * HC + 16 + 4 * g + reg] : 0.f;
  }
  float alpha = salpha[0], beta = sbeta[0];
  size_t simbase = (((size_t)b * HEADS + wv) * OCT + o) * (size_t)NPTS + (size_t)chunk * 128;

  f32x4 accL[M], accU[M];
  float accD[M];
#pragma unroll
  for (int m = 0; m < M; m++) {
    accL[m] = (f32x4){0.f, 0.f, 0.f, 0.f};
    accU[m] = (f32x4){0.f, 0.f, 0.f, 0.f};
    accD[m] = 0.f;
  }

  __syncthreads();

#pragma unroll 1
  for (int pt = 0; pt < 8; pt++) {
    f32x4 a0, a1, a2, a3;
#pragma unroll
    for (int reg = 0; reg < 4; reg++) {
      a0[reg] = bF0[reg]; a1[reg] = bF1[reg];
      a2[reg] = bV0[reg]; a3[reg] = bV1[reg];
    }
#pragma unroll
    for (int kb = 0; kb < 2; kb++) {
      bf16x8 xh = *(const bf16x8*)&Bh[pt][kb][lane];
      bf16x8 xm = *(const bf16x8*)&Bm[pt][kb][lane];
      a0 = __builtin_amdgcn_mfma_f32_16x16x32_bf16(Fh[0][kb], xh, a0, 0, 0, 0);
      a0 = __builtin_amdgcn_mfma_f32_16x16x32_bf16(Fh[0][kb], xm, a0, 0, 0, 0);
      a0 = __builtin_amdgcn_mfma_f32_16x16x32_bf16(Fm[0][kb], xh, a0, 0, 0, 0);
      a1 = __builtin_amdgcn_mfma_f32_16x16x32_bf16(Fh[1][kb], xh, a1, 0, 0, 0);
      a1 = __builtin_amdgcn_mfma_f32_16x16x32_bf16(Fh[1][kb], xm, a1, 0, 0, 0);
      a1 = __builtin_amdgcn_mfma_f32_16x16x32_bf16(Fm[1][kb], xh, a1, 0, 0, 0);
      a2 = __builtin_amdgcn_mfma_f32_16x16x32_bf16(Vh[0][kb], xh, a2, 0, 0, 0);
      a2 = __builtin_amdgcn_mfma_f32_16x16x32_bf16(Vh[0][kb], xm, a2, 0, 0, 0);
      a2 = __builtin_amdgcn_mfma_f32_16x16x32_bf16(Vm[0][kb], xh, a2, 0, 0, 0);
      a3 = __builtin_amdgcn_mfma_f32_16x16x32_bf16(Vh[1][kb], xh, a3, 0, 0, 0);
      a3 = __builtin_amdgcn_mfma_f32_16x16x32_bf16(Vh[1][kb], xm, a3, 0, 0, 0);
      a3 = __builtin_amdgcn_mfma_f32_16x16x32_bf16(Vm[1][kb], xh, a3, 0, 0, 0);
    }
    float ss = 0.f;
#pragma unroll
    for (int reg = 0; reg < 4; reg++) ss += a0[reg] * a0[reg];
    if (g < 2) {
#pragma unroll
      for (int reg = 0; reg < 4; reg++) ss += a1[reg] * a1[reg];
    }
    ss += __shfl_xor(ss, 16, 64); ss += __shfl_xor(ss, 32, 64);
    float rinv = 1.f / fmaxf(sqrtf(ss), 1e-12f);
    float dm[M];
#pragma unroll
    for (int mm = 0; mm < 4; mm++) {
      dm[mm]     = __shfl(a1[mm], 32 + p16, 64);
      dm[4 + mm] = __shfl(a1[mm], 48 + p16, 64);
    }
    float bs = -1.f, bs2 = -1.f; int bm = 0;
#pragma unroll
    for (int m = 0; m < M; m++) {
      float sim = 1.f / (1.f + __expf(-(beta + alpha * (dm[m] * rinv))));
      if (sim > bs) { bs2 = bs; bs = sim; bm = m; }
      else if (sim > bs2) bs2 = sim;
    }
    bool need = (bs - bs2) < 3e-5f;
    if (__any(need ? 1 : 0)) {
      int npnt = chunk * 128 + pt * 16 + p16;
      int wp_ = npnt / 576, hp_ = (npnt / 24) % 24, dp_ = npnt % 24;
      const float* xq = x + (size_t)b * CIN * SPAT
                      + (size_t)((ow * 24 + wp_) * S + (oh * 24 + hp_)) * S + (od * 24 + dp_);
      int c0 = g * 6;
      float f6[6];
#pragma unroll
      for (int j = 0; j < 6; j++) f6[j] = bf_[wv * HC + c0 + j];
      if (need) {
#pragma unroll 1
        for (int ci = 0; ci < CIN; ci++) {
          float xv = xq[(size_t)ci * SPAT];
#pragma unroll
          for (int j = 0; j < 6; j++)
            f6[j] += Wf[(wv * HC + c0 + j) * CIN + ci] * xv;
        }
      }
#pragma unroll
      for (int j = 0; j < 6; j++) lds_fq[wv][p16][c0 + j] = f6[j];
      float ss2 = 0.f, dt0 = 0.f, dt1 = 0.f;
      const float* cnb2 = cnorm + (((size_t)b * HEADS + wv) * OCT + o) * M * HC;
      int m0 = 2 * g, m1 = 2 * g + 1;
      if (need) {
#pragma unroll 1
        for (int c = 0; c < HC; c++) {
          float fv = lds_fq[wv][p16][c];
          ss2 += fv * fv;
          dt0 += cnb2[m0 * HC + c] * fv;
          dt1 += cnb2[m1 * HC + c] * fv;
        }
      }
      float dtg[8];
#pragma unroll
      for (int gg2 = 0; gg2 < 4; gg2++) {
        dtg[2 * gg2]     = __shfl(dt0, p16 + 16 * gg2, 64);
        dtg[2 * gg2 + 1] = __shfl(dt1, p16 + 16 * gg2, 64);
      }
      if (need) {
        float rinv2 = 1.f / fmaxf(sqrtf(ss2), 1e-12f);
        float best = -1.f; int bq = 0;
#pragma unroll
        for (int m = 0; m < M; m++) {
          float sim = 1.f / (1.f + __expf(-(beta + alpha * (dtg[m] * rinv2))));
          if (sim > best) { best = sim; bq = m; }
        }
        bs = best; bm = bq;
      }
    }
    unsigned int bsbits = __float_as_uint(bs) & ~7u;
    float bsm = __uint_as_float(bsbits);
    if (lane < 16) {
      simidx[simbase + pt * 16 + p16] = bsbits | (unsigned int)bm;
    }
#pragma unroll
    for (int m = 0; m < M; m++) {
      float w = (bm == m) ? bsm : 0.f;
#pragma unroll
      for (int reg = 0; reg < 4; reg++) {
        accL[m][reg] += w * a2[reg];
        accU[m][reg] += w * a3[reg];
      }
      if (g == 0) accD[m] += w;
    }
  }

  // ---- reduce over the 16 lanes of each g-group; plain LDS stores ----
#pragma unroll
  for (int m = 0; m < M; m++) {
#pragma unroll
    for (int reg = 0; reg < 4; reg++) {
      float vL = accL[m][reg];
      vL += __shfl_xor(vL, 1, 64); vL += __shfl_xor(vL, 2, 64);
      vL += __shfl_xor(vL, 4, 64); vL += __shfl_xor(vL, 8, 64);
      if (p16 == 0) lds_agg[wv][m][4 * g + reg] = vL;
      float vU = accU[m][reg];
      vU += __shfl_xor(vU, 1, 64); vU += __shfl_xor(vU, 2, 64);
      vU += __shfl_xor(vU, 4, 64); vU += __shfl_xor(vU, 8, 64);
      if (p16 == 0 && g < 2) lds_agg[wv][m][16 + 4 * g + reg] = vU;
    }
    float vD = accD[m];
    vD += __shfl_xor(vD, 1, 64); vD += __shfl_xor(vD, 2, 64);
    vD += __shfl_xor(vD, 4, 64); vD += __shfl_xor(vD, 8, 64);
    if (lane == 0) lds_den[wv][m] = vD;
  }
  __syncthreads();

  for (int i = t; i < HEADS * M * HC; i += 256) {
    int e = i / (M * HC), r = i % (M * HC);
    int m = r / HC, c = r % HC;
    atomicAdd(&aggnum[((((size_t)b * HEADS + e) * OCT + o) * M + m) * HC + c],
              lds_agg[e][m][c]);
  }
  if (t < HEADS * M) {
    int e = t / M, m = t % M;
    atomicAdd(&aggden[(((size_t)b * HEADS + e) * OCT + o) * M + m], lds_den[e][m]);
  }
}

// ---------------- Kernel 3: MFMA dispatch + projection (64-pt tile) ----------
__global__ __launch_bounds__(256) void k_out(
    const unsigned short* __restrict__ wsP_h, const unsigned short* __restrict__ wsP_l,
    const float* __restrict__ bp,
    const float* __restrict__ aggnum, const float* __restrict__ aggden,
    const unsigned int* __restrict__ simidx,
    float* __restrict__ out) {
  int blk = blockIdx.x;
  int chunk = blk % 216;
  int bo = blk / 216;
  int o = bo & 7, b = bo >> 3;
  int t = threadIdx.x, lane = t & 63, wvid = t >> 6;
  int p16 = lane & 15, g = lane >> 4;

  __shared__ uint4 Bh[4][3][64], Bl[4][3][64];
  __shared__ float lds_agg[HEADS][M][HC];
  __shared__ float lds_den[HEADS][M];

  for (int i = t; i < HEADS * M * HC; i += 256) {
    int e = i / (M * HC), r = i % (M * HC);
    int m = r / HC, c = r % HC;
    ((float*)lds_agg)[i] = aggnum[((((size_t)b * HEADS + e) * OCT + o) * M + m) * HC + c];
  }
  if (t < HEADS * M) {
    int e = t / M, m = t % M;
    ((float*)lds_den)[t] = aggden[(((size_t)b * HEADS + e) * OCT + o) * M + m];
  }
  __syncthreads();

  // staging: 4 threads per point, 3 (kb,gs) groups each
  {
    int pidx = t >> 2, q = t & 3;
    int n = chunk * 64 + pidx;
    int pt = pidx >> 4, pw = pidx & 15;
    float rat[4]; int mm[4];
#pragma unroll
    for (int e = 0; e < 4; e++) {
      size_t pidx2 = (((size_t)b * HEADS + e) * OCT + o) * (size_t)NPTS + n;
      unsigned int bits = simidx[pidx2];
      int m = (int)(bits & 7u);
      float s = __uint_as_float(bits & ~7u);
      mm[e] = m;
      rat[e] = s / lds_den[e][m];
    }
#pragma unroll
    for (int gi = 0; gi < 3; gi++) {
      int grp = q * 3 + gi;
      int kb = grp >> 2, gs = grp & 3;
      unsigned int ph[4], pl[4];
#pragma unroll
      for (int jj = 0; jj < 4; jj++) {
        unsigned short h2[2], l2[2];
#pragma unroll
        for (int k2 = 0; k2 < 2; k2++) {
          int kk = kb * 32 + gs * 8 + jj * 2 + k2;
          int e = kk / HC, c = kk % HC;
          float pre = lds_agg[e][mm[e]][c] * rat[e];
          unsigned short h = f2bf(pre);
          h2[k2] = h; l2[k2] = f2bf(pre - bf2f(h));
        }
        ph[jj] = (unsigned)h2[0] | ((unsigned)h2[1] << 16);
        pl[jj] = (unsigned)l2[0] | ((unsigned)l2[1] << 16);
      }
      Bh[pt][kb][gs * 16 + pw] = make_uint4(ph[0], ph[1], ph[2], ph[3]);
      Bl[pt][kb][gs * 16 + pw] = make_uint4(pl[0], pl[1], pl[2], pl[3]);
    }
  }
  __syncthreads();

  const bf16x8* PH = (const bf16x8*)wsP_h;
  const bf16x8* PL = (const bf16x8*)wsP_l;
  bf16x8 Ah[3], Al[3];
#pragma unroll
  for (int kb = 0; kb < 3; kb++) {
    Ah[kb] = PH[(wvid * 3 + kb) * 64 + lane];
    Al[kb] = PL[(wvid * 3 + kb) * 64 + lane];
  }
  float bpv[4];
#pragma unroll
  for (int reg = 0; reg < 4; reg++) bpv[reg] = bp[wvid * 16 + 4 * g + reg];

  int ow = (o >> 2) & 1, oh = (o >> 1) & 1, od = o & 1;
#pragma unroll 1
  for (int pt = 0; pt < 4; pt++) {
    f32x4 acc;
#pragma unroll
    for (int reg = 0; reg < 4; reg++) acc[reg] = bpv[reg];
#pragma unroll
    for (int kb = 0; kb < 3; kb++) {
      bf16x8 bh = *(const bf16x8*)&Bh[pt][kb][lane];
      bf16x8 bl = *(const bf16x8*)&Bl[pt][kb][lane];
      acc = __builtin_amdgcn_mfma_f32_16x16x32_bf16(Ah[kb], bh, acc, 0, 0, 0);
      acc = __builtin_amdgcn_mfma_f32_16x16x32_bf16(Ah[kb], bl, acc, 0, 0, 0);
      acc = __builtin_amdgcn_mfma_f32_16x16x32_bf16(Al[kb], bh, acc, 0, 0, 0);
    }
    int np = chunk * 64 + pt * 16 + p16;
    int wp = np / 576, hp = (np / 24) % 24, dp = np % 24;
    float* ob = out + (size_t)b * CIN * SPAT
              + (size_t)((ow * 24 + wp) * S + (oh * 24 + hp)) * S + (od * 24 + dp);
#pragma unroll
    for (int reg = 0; reg < 4; reg++)
      ob[(size_t)(wvid * 16 + 4 * g + reg) * SPAT] = acc[reg];
  }
}

extern "C" void kernel_launch(void* const* d_in, const int* in_sizes, int n_in,
                              void* d_out, int out_size, void* d_ws, size_t ws_size,
                              hipStream_t stream) {
  const float* x  = (const float*)d_in[0];
  const float* Wf = (const float*)d_in[1];
  const float* bf_ = (const float*)d_in[2];
  const float* Wv = (const float*)d_in[3];
  const float* bv_ = (const float*)d_in[4];
  const float* Wp = (const float*)d_in[5];
  const float* bp = (const float*)d_in[6];
  const float* sa = (const float*)d_in[7];
  const float* sb = (const float*)d_in[8];
  float* out = (float*)d_out;

  // Layout identical to rounds 16-20 (7.81 MB); wsA_l / wsG_l regions unused.
  float* ws = (float*)d_ws;
  float* cnorm  = ws;
  float* aggnum = ws + 24576;
  float* aggden = ws + 49152;
  unsigned int* simidx = (unsigned int*)(ws + 50176);        // -> 1819648
  unsigned short* wsA_h = (unsigned short*)(ws + 1819648);
  unsigned short* wsA_m = (unsigned short*)(ws + 1827840);
  unsigned short* wsP_h = (unsigned short*)(ws + 1844224);
  unsigned short* wsP_l = (unsigned short*)(ws + 1847296);
  unsigned short* wsG_h = (unsigned short*)(ws + 1850368);
  unsigned short* wsG_m = (unsigned short*)(ws + 1915904);
  float* biasG = ws + 2046976;

  k_prep<<<1, 256, 0, stream>>>(Wf, Wv, Wp, wsA_h, wsA_m, wsP_h, wsP_l);
  k_centers<<<BATCH * 64, 256, 0, stream>>>(x, Wf, bf_, Wv, bv_, cnorm, aggnum, aggden,
                                            wsG_h, wsG_m, biasG);
  k_assign<<<BATCH * OCT * 108, 256, 0, stream>>>(x, Wf, wsA_h, wsA_m,
                                                  wsG_h, wsG_m, biasG,
                                                  bf_, bv_, cnorm, sa, sb,
                                                  aggnum, aggden, simidx);
  k_out<<<BATCH * OCT * 216, 256, 0, stream>>>(wsP_h, wsP_l, bp, aggnum, aggden,
                                               simidx, out);
}